// Round 10
// baseline (190.103 us; speedup 1.0000x reference)
//
#include <hip/hip_runtime.h>

// PointPillarScatter3d on MI355X (gfx950)
// NZ=1, NY=NX=512, C=128, B=4, P=320000.
// Strategy: scatter->gather inversion (R9 geometry) + T1 XCD-aware block swizzle.
//   hipMemsetAsync: map[B*CELLS] = -1
//   k_scatter_idx:  map[b*CELLS + cell] = point index (cells unique per batch)
//   k_gather:       256-cell tile x all 128 channels, 1024 threads, 2 barriers.
//     Phase B: full 512B row gathers (32 lanes x float4/row), scalar LDS writes
//              (4-way aliasing, proven non-critical R2/R6).
//     Phase C: per channel, ONE wave instr = 64 lanes x 16B = 1KB contiguous run.
//   T1 swizzle: 4096 blocks, 4096%8==0 -> bijective swz=(bid&7)*512+(bid>>3).
//     Each XCD owns 512 CONSECUTIVE tiles: its private L2 sees adjacent 1KB
//     chunks per channel plane and evicts long sequential per-channel runs,
//     instead of 8 XCDs interleaving scattered chunks at DRAM.
//   Full output covered -> zeros from LDS for empty cells, no separate zero pass.

#define NXD 512
#define NYD 512
#define NZD 1
#define CB  128
#define CELLS (NXD * NYD * NZD)   // 262144

#define TILE 256                  // cells per block
#define NTHR 1024                 // 16 waves; 1 block/CU = 16 waves/CU
#define NXCD 8

typedef float f4 __attribute__((ext_vector_type(4)));

__global__ void k_scatter_idx(const int* __restrict__ coords,
                              int* __restrict__ map, int P) {
    int p = blockIdx.x * blockDim.x + threadIdx.x;
    if (p >= P) return;
    int4 c = ((const int4*)coords)[p];      // (b, z, y, x)
    int cell = c.y * (NYD * NXD) + c.z * NXD + c.w;
    map[c.x * CELLS + cell] = p;
}

__global__ __launch_bounds__(NTHR) void k_gather(const float* __restrict__ feat,
                                                 const int* __restrict__ map,
                                                 float* __restrict__ out,
                                                 int nblk) {
    __shared__ int pidx[TILE];
    __shared__ f4  ldsC[CB][TILE / 4];      // [channel][x-slot], swizzled; 128 KB

    // T1: XCD-aware bijective swizzle (nblk % 8 == 0 guaranteed by launch).
    const int chunk = nblk / NXCD;
    const int bid   = (blockIdx.x & (NXCD - 1)) * chunk + (blockIdx.x >> 3);

    const int t = threadIdx.x;
    const int tiles_per_b = CELLS / TILE;   // 1024
    const int b = bid / tiles_per_b;
    const int cell_base = (bid % tiles_per_b) * TILE;

    if (t < TILE) pidx[t] = map[b * CELLS + cell_base + t];
    __syncthreads();

    // Phase B: 32 lanes x float4 = one 512B row; 32 rows in flight, 8 passes.
    {
        const int c4 = t & 31;     // float4 column within row (channels 4c4..4c4+3)
        const int r0 = t >> 5;     // 0..31
        int idxr[8];
        #pragma unroll
        for (int rr = 0; rr < 8; ++rr) idxr[rr] = pidx[rr * 32 + r0];
        #pragma unroll
        for (int rr = 0; rr < 8; ++rr) {
            const int x = rr * 32 + r0;
            f4 v = (f4)(0.f);
            if (idxr[rr] >= 0)
                v = ((const f4*)feat)[(size_t)idxr[rr] * (CB / 4) + c4];
            const int slot = (x >> 2) ^ (c4 & 7);
            const int xe   = x & 3;
            ((float*)&ldsC[c4 * 4 + 0][slot])[xe] = v.x;
            ((float*)&ldsC[c4 * 4 + 1][slot])[xe] = v.y;
            ((float*)&ldsC[c4 * 4 + 2][slot])[xe] = v.z;
            ((float*)&ldsC[c4 * 4 + 3][slot])[xe] = v.w;
        }
    }
    __syncthreads();

    // Phase C: per channel, one conflict-free b128 read + 64 lanes x float4
    // = 1KB contiguous store. 16 channels in flight, 8 passes.
    {
        const int x4 = t & 63;     // float4 index along 256 cells
        const int cr = t >> 6;     // 0..15
        float* outb = out + (size_t)b * CB * CELLS + cell_base;
        #pragma unroll
        for (int cc = 0; cc < 8; ++cc) {
            const int c = cc * 16 + cr;
            f4 v = ldsC[c][x4 ^ ((c >> 2) & 7)];
            *reinterpret_cast<f4*>(outb + (size_t)c * CELLS + x4 * 4) = v;
        }
    }
}

extern "C" void kernel_launch(void* const* d_in, const int* in_sizes, int n_in,
                              void* d_out, int out_size, void* d_ws, size_t ws_size,
                              hipStream_t stream) {
    const float* feat   = (const float*)d_in[1];
    const int*   coords = (const int*)d_in[2];
    float*       out    = (float*)d_out;
    int*         map    = (int*)d_ws;   // B*CELLS int32 = 4 MB

    const int B = out_size / (CB * CELLS);
    const int P = in_sizes[1] / CB;
    const int n_map = B * CELLS;
    const int nblk  = B * (CELLS / TILE);   // 4096, %8==0 -> bijective swizzle

    (void)hipMemsetAsync(map, 0xFF, (size_t)n_map * sizeof(int), stream);
    k_scatter_idx<<<(P + 255) / 256, 256, 0, stream>>>(coords, map, P);
    k_gather<<<nblk, NTHR, 0, stream>>>(feat, map, out, nblk);
}